// Round 1
// baseline (2696.809 us; speedup 1.0000x reference)
//
#include <hip/hip_runtime.h>
#include <hip/hip_bf16.h>

#define NPIX 6400
#define IMW 80
#define IMH 80

__device__ __forceinline__ float silu_f(float v) {
    return v / (1.0f + __expf(-v));
}

// ---------------- cv1: y = silu(W1 @ x + b1), stored bf16 ----------------
__global__ __launch_bounds__(256) void cv1_kernel(
    const float* __restrict__ x, const float* __restrict__ W1,
    const float* __restrict__ b1, __hip_bfloat16* __restrict__ y)
{
    const int b   = blockIdx.z;
    const int p0  = blockIdx.x * 64;
    const int co0 = blockIdx.y * 64;
    __shared__ float As[16][64];
    __shared__ float Bs[16][64];
    const int tid = threadIdx.x;
    const int tn = tid & 15;   // 16 n-groups of 4 cols
    const int tm = tid >> 4;   // 16 m-groups of 4 rows
    float acc[4][4] = {};
    const float* xb = x + (size_t)b * 256 * NPIX;
    for (int k0 = 0; k0 < 256; k0 += 16) {
        #pragma unroll
        for (int i = 0; i < 4; i++) {
            int e = tid + i * 256;
            int m = e >> 4, k = e & 15;
            As[k][m] = W1[(co0 + m) * 256 + (k0 + k)];
        }
        #pragma unroll
        for (int i = 0; i < 4; i++) {
            int e = tid + i * 256;
            int k = e >> 6, n = e & 63;
            Bs[k][n] = xb[(size_t)(k0 + k) * NPIX + (p0 + n)];
        }
        __syncthreads();
        #pragma unroll
        for (int k = 0; k < 16; k++) {
            float4 av = *(const float4*)&As[k][tm * 4];
            float4 bv = *(const float4*)&Bs[k][tn * 4];
            float a[4] = {av.x, av.y, av.z, av.w};
            float bb[4] = {bv.x, bv.y, bv.z, bv.w};
            #pragma unroll
            for (int i2 = 0; i2 < 4; i2++)
                #pragma unroll
                for (int j = 0; j < 4; j++)
                    acc[i2][j] += a[i2] * bb[j];
        }
        __syncthreads();
    }
    #pragma unroll
    for (int i = 0; i < 4; i++) {
        int co = co0 + tm * 4 + i;
        float bias = b1[co];
        size_t base = ((size_t)b * 256 + co) * NPIX + p0 + tn * 4;
        #pragma unroll
        for (int j = 0; j < 4; j++) {
            float v = acc[i][j] + bias;
            y[base + j] = __float2bfloat16(silu_f(v));
        }
    }
}

// ---------------- pooling: pooled[b][c] = mean over HW of m ----------------
__global__ __launch_bounds__(256) void pool_kernel(
    const __hip_bfloat16* __restrict__ y, float* __restrict__ pooled)
{
    const int c = blockIdx.x;
    const int b = blockIdx.y;
    const __hip_bfloat16* src = y + ((size_t)b * 256 + 128 + c) * NPIX;
    float s = 0.f;
    for (int p = threadIdx.x; p < NPIX; p += 256)
        s += __bfloat162float(src[p]);
    #pragma unroll
    for (int off = 32; off > 0; off >>= 1)
        s += __shfl_down(s, off, 64);
    __shared__ float red[4];
    int lane = threadIdx.x & 63, wv = threadIdx.x >> 6;
    if (lane == 0) red[wv] = s;
    __syncthreads();
    if (threadIdx.x == 0) {
        float t = red[0] + red[1] + red[2] + red[3];
        pooled[b * 128 + c] = t * (1.0f / NPIX);
    }
}

// ---------------- router: softmax + top2 + renorm ----------------
__global__ __launch_bounds__(64) void router_kernel(
    const float* __restrict__ pooled, const float* __restrict__ Wr,
    const float* __restrict__ br, int* __restrict__ sel_idx, float* __restrict__ sel_w)
{
    __shared__ float lg[16][4];
    int tid = threadIdx.x;
    int b = tid >> 2, e = tid & 3;
    float s = br[e];
    for (int c2 = 0; c2 < 128; c2++)
        s += pooled[b * 128 + c2] * Wr[e * 128 + c2];
    lg[b][e] = s;
    __syncthreads();
    if (tid < 16) {
        int bb = tid;
        float l[4]; float mx = -1e30f;
        #pragma unroll
        for (int i = 0; i < 4; i++) { l[i] = lg[bb][i]; mx = fmaxf(mx, l[i]); }
        float p[4]; float sum = 0.f;
        #pragma unroll
        for (int i = 0; i < 4; i++) { p[i] = __expf(l[i] - mx); sum += p[i]; }
        #pragma unroll
        for (int i = 0; i < 4; i++) p[i] /= sum;
        int i1 = 0;
        for (int i = 1; i < 4; i++) if (p[i] > p[i1]) i1 = i;   // ties -> lowest idx
        int i2 = (i1 == 0) ? 1 : 0;
        for (int i = 0; i < 4; i++) if (i != i1 && p[i] > p[i2]) i2 = i;
        float inv = 1.0f / (p[i1] + p[i2]);
        sel_idx[bb * 2 + 0] = i1; sel_idx[bb * 2 + 1] = i2;
        sel_w[bb * 2 + 0] = p[i1] * inv; sel_w[bb * 2 + 1] = p[i2] * inv;
    }
}

// ---------------- expert conv: moe = sum_k w_k * silu(conv3x3(m, W_e_k) + b) ----------------
// grid: (row-pairs=40, co-tiles=4, b=16), block 320
// thread tile: 4co x 1row x 4x; out tile per block: 32co x 2rows x 80x
__global__ __launch_bounds__(320) void expert_kernel(
    const __hip_bfloat16* __restrict__ y, const float* __restrict__ Wexp,
    const float* __restrict__ bexp, const int* __restrict__ sel_idx,
    const float* __restrict__ sel_w, __hip_bfloat16* __restrict__ moe)
{
    const int b      = blockIdx.z;
    const int cobase = blockIdx.y * 32;
    const int r0     = blockIdx.x * 2;
    __shared__ float mld[16][4][84];      // [ci][row(-1..+2)][col(-1..80), padded to 84]
    __shared__ float wld[16 * 32 * 12];   // [ci][co][tap, padded to 12]
    const int tid = threadIdx.x;
    const int xg  = tid % 20;
    const int rr  = (tid / 20) & 1;
    const int cog = tid / 40;             // 0..7
    const int xo  = xg * 4;
    float outacc[4][4] = {};
    for (int kk = 0; kk < 2; kk++) {
        const int   e  = sel_idx[b * 2 + kk];
        const float gw = sel_w[b * 2 + kk];
        float acc[4][4] = {};
        const float* wsrc = Wexp + (size_t)e * 128 * 128 * 9;
        for (int c0 = 0; c0 < 128; c0 += 16) {
            for (int idx = tid; idx < 16 * 4 * 84; idx += 320) {
                int ci = idx / 336, rem = idx % 336;
                int row = rem / 84, col = rem % 84;
                int gr = r0 - 1 + row, gc = col - 1;
                float v = 0.f;
                if (gr >= 0 && gr < IMH && gc >= 0 && gc < IMW)
                    v = __bfloat162float(
                        y[((size_t)b * 256 + 128 + c0 + ci) * NPIX + gr * IMW + gc]);
                mld[ci][row][col] = v;
            }
            for (int idx = tid; idx < 16 * 32 * 9; idx += 320) {
                int ci = idx / 288, rem = idx % 288;
                int co = rem / 9, tap = rem % 9;
                wld[(ci * 32 + co) * 12 + tap] =
                    wsrc[((size_t)(cobase + co) * 128 + (c0 + ci)) * 9 + tap];
            }
            __syncthreads();
            #pragma unroll 4
            for (int ci = 0; ci < 16; ci++) {
                float mv[3][6];
                #pragma unroll
                for (int dy = 0; dy < 3; dy++) {
                    const float* mp = &mld[ci][rr + dy][xo];
                    float4 m4 = *(const float4*)mp;
                    float2 m2 = *(const float2*)(mp + 4);
                    mv[dy][0] = m4.x; mv[dy][1] = m4.y; mv[dy][2] = m4.z;
                    mv[dy][3] = m4.w; mv[dy][4] = m2.x; mv[dy][5] = m2.y;
                }
                #pragma unroll
                for (int c = 0; c < 4; c++) {
                    const float* wp = &wld[(ci * 32 + cog * 4 + c) * 12];
                    float4 wa = *(const float4*)wp;
                    float4 wb = *(const float4*)(wp + 4);
                    float w8 = wp[8];
                    float wt[9] = {wa.x, wa.y, wa.z, wa.w, wb.x, wb.y, wb.z, wb.w, w8};
                    #pragma unroll
                    for (int dy = 0; dy < 3; dy++)
                        #pragma unroll
                        for (int dx = 0; dx < 3; dx++) {
                            float w = wt[dy * 3 + dx];
                            #pragma unroll
                            for (int j = 0; j < 4; j++)
                                acc[c][j] += w * mv[dy][j + dx];
                        }
                }
            }
            __syncthreads();
        }
        #pragma unroll
        for (int c = 0; c < 4; c++) {
            float bias = bexp[e * 128 + cobase + cog * 4 + c];
            #pragma unroll
            for (int j = 0; j < 4; j++)
                outacc[c][j] += gw * silu_f(acc[c][j] + bias);
        }
    }
    const int row = r0 + rr;
    #pragma unroll
    for (int c = 0; c < 4; c++) {
        size_t base = ((size_t)b * 128 + cobase + cog * 4 + c) * NPIX + row * IMW + xo;
        #pragma unroll
        for (int j = 0; j < 4; j++)
            moe[base + j] = __float2bfloat16(outacc[c][j]);
    }
}

// ---------------- cv2: out = silu(W2 @ concat[a,m,moe] + b2), fp32 out ----------------
__global__ __launch_bounds__(256) void cv2_kernel(
    const __hip_bfloat16* __restrict__ y, const __hip_bfloat16* __restrict__ moe,
    const float* __restrict__ W2, const float* __restrict__ b2,
    float* __restrict__ out)
{
    const int b   = blockIdx.z;
    const int p0  = blockIdx.x * 64;
    const int co0 = blockIdx.y * 64;
    __shared__ float As[16][64];
    __shared__ float Bs[16][64];
    const int tid = threadIdx.x;
    const int tn = tid & 15;
    const int tm = tid >> 4;
    float acc[4][4] = {};
    for (int k0 = 0; k0 < 384; k0 += 16) {
        #pragma unroll
        for (int i = 0; i < 4; i++) {
            int e = tid + i * 256;
            int m = e >> 4, k = e & 15;
            As[k][m] = W2[(co0 + m) * 384 + (k0 + k)];
        }
        #pragma unroll
        for (int i = 0; i < 4; i++) {
            int e = tid + i * 256;
            int k = e >> 6, n = e & 63;
            int jch = k0 + k;
            float v;
            if (jch < 256)
                v = __bfloat162float(y[((size_t)b * 256 + jch) * NPIX + p0 + n]);
            else
                v = __bfloat162float(moe[((size_t)b * 128 + (jch - 256)) * NPIX + p0 + n]);
            Bs[k][n] = v;
        }
        __syncthreads();
        #pragma unroll
        for (int k = 0; k < 16; k++) {
            float4 av = *(const float4*)&As[k][tm * 4];
            float4 bv = *(const float4*)&Bs[k][tn * 4];
            float a[4] = {av.x, av.y, av.z, av.w};
            float bb[4] = {bv.x, bv.y, bv.z, bv.w};
            #pragma unroll
            for (int i2 = 0; i2 < 4; i2++)
                #pragma unroll
                for (int j = 0; j < 4; j++)
                    acc[i2][j] += a[i2] * bb[j];
        }
        __syncthreads();
    }
    #pragma unroll
    for (int i = 0; i < 4; i++) {
        int co = co0 + tm * 4 + i;
        float bias = b2[co];
        size_t base = ((size_t)b * 256 + co) * NPIX + p0 + tn * 4;
        #pragma unroll
        for (int j = 0; j < 4; j++) {
            float v = acc[i][j] + bias;
            out[base + j] = silu_f(v);
        }
    }
}

extern "C" void kernel_launch(void* const* d_in, const int* in_sizes, int n_in,
                              void* d_out, int out_size, void* d_ws, size_t ws_size,
                              hipStream_t stream)
{
    (void)in_sizes; (void)n_in; (void)out_size; (void)ws_size;
    const float* x    = (const float*)d_in[0];
    const float* W1   = (const float*)d_in[1];
    const float* b1   = (const float*)d_in[2];
    const float* Wr   = (const float*)d_in[3];
    const float* br   = (const float*)d_in[4];
    const float* Wexp = (const float*)d_in[5];
    const float* bexp = (const float*)d_in[6];
    const float* W2   = (const float*)d_in[7];
    const float* b2   = (const float*)d_in[8];
    float* out = (float*)d_out;

    char* ws = (char*)d_ws;
    // layout: y bf16 (52,428,800 B) | moe bf16 (26,214,400 B) | pooled | sel
    __hip_bfloat16* y   = (__hip_bfloat16*)ws;
    __hip_bfloat16* moe = (__hip_bfloat16*)(ws + 52428800);
    float* pooled       = (float*)(ws + 78643200);
    int*   sel_idx      = (int*)(ws + 78651392);
    float* sel_w        = (float*)(ws + 78651520);

    cv1_kernel   <<<dim3(100, 4, 16), 256, 0, stream>>>(x, W1, b1, y);
    pool_kernel  <<<dim3(128, 16),    256, 0, stream>>>(y, pooled);
    router_kernel<<<1,                 64, 0, stream>>>(pooled, Wr, br, sel_idx, sel_w);
    expert_kernel<<<dim3(40, 4, 16),  320, 0, stream>>>(y, Wexp, bexp, sel_idx, sel_w, moe);
    cv2_kernel   <<<dim3(100, 4, 16), 256, 0, stream>>>(y, moe, W2, b2, out);
}

// Round 2
// 941.334 us; speedup vs baseline: 2.8649x; 2.8649x over previous
//
#include <hip/hip_runtime.h>
#include <hip/hip_bf16.h>

#define NPIX 6400
#define IMW 80
#define IMH 80

typedef __attribute__((ext_vector_type(8))) short short8;
typedef __attribute__((ext_vector_type(4))) float floatx4;

__device__ __forceinline__ float silu_f(float v) {
    return v / (1.0f + __expf(-v));
}

// ---------------- cv1: y = silu(W1 @ x + b1), stored bf16 ----------------
__global__ __launch_bounds__(256) void cv1_kernel(
    const float* __restrict__ x, const float* __restrict__ W1,
    const float* __restrict__ b1, __hip_bfloat16* __restrict__ y)
{
    const int b   = blockIdx.z;
    const int p0  = blockIdx.x * 64;
    const int co0 = blockIdx.y * 64;
    __shared__ float As[16][64];
    __shared__ float Bs[16][64];
    const int tid = threadIdx.x;
    const int tn = tid & 15;
    const int tm = tid >> 4;
    float acc[4][4] = {};
    const float* xb = x + (size_t)b * 256 * NPIX;
    for (int k0 = 0; k0 < 256; k0 += 16) {
        #pragma unroll
        for (int i = 0; i < 4; i++) {
            int e = tid + i * 256;
            int m = e >> 4, k = e & 15;
            As[k][m] = W1[(co0 + m) * 256 + (k0 + k)];
        }
        #pragma unroll
        for (int i = 0; i < 4; i++) {
            int e = tid + i * 256;
            int k = e >> 6, n = e & 63;
            Bs[k][n] = xb[(size_t)(k0 + k) * NPIX + (p0 + n)];
        }
        __syncthreads();
        #pragma unroll
        for (int k = 0; k < 16; k++) {
            float4 av = *(const float4*)&As[k][tm * 4];
            float4 bv = *(const float4*)&Bs[k][tn * 4];
            float a[4] = {av.x, av.y, av.z, av.w};
            float bb[4] = {bv.x, bv.y, bv.z, bv.w};
            #pragma unroll
            for (int i2 = 0; i2 < 4; i2++)
                #pragma unroll
                for (int j = 0; j < 4; j++)
                    acc[i2][j] += a[i2] * bb[j];
        }
        __syncthreads();
    }
    #pragma unroll
    for (int i = 0; i < 4; i++) {
        int co = co0 + tm * 4 + i;
        float bias = b1[co];
        size_t base = ((size_t)b * 256 + co) * NPIX + p0 + tn * 4;
        #pragma unroll
        for (int j = 0; j < 4; j++) {
            float v = acc[i][j] + bias;
            y[base + j] = __float2bfloat16(silu_f(v));
        }
    }
}

// ---------------- transpose m-half of y -> mT[b][pix][ci] bf16 ----------------
__global__ __launch_bounds__(256) void transpose_m(
    const __hip_bfloat16* __restrict__ y, __hip_bfloat16* __restrict__ mT)
{
    const int b   = blockIdx.z;
    const int ci0 = blockIdx.y * 64;
    const int p0  = blockIdx.x * 64;
    __shared__ unsigned short t[64][68];
    const int tid = threadIdx.x;
    const unsigned short* src =
        (const unsigned short*)y + ((size_t)b * 256 + 128 + ci0) * NPIX + p0;
    #pragma unroll
    for (int it = 0; it < 4; ++it) {
        int idx = tid + it * 256;          // 0..1023
        int ci = idx >> 4, pg = idx & 15;
        uint2 v = *(const uint2*)(src + (size_t)ci * NPIX + pg * 4);
        *(uint2*)&t[ci][pg * 4] = v;
    }
    __syncthreads();
    unsigned short* dst = (unsigned short*)mT + ((size_t)b * NPIX + p0) * 128 + ci0;
    #pragma unroll
    for (int it = 0; it < 4; ++it) {
        int idx = tid + it * 256;
        int p = idx >> 4, cg = idx & 15;
        unsigned short vv[4];
        #pragma unroll
        for (int j = 0; j < 4; ++j) vv[j] = t[cg * 4 + j][p];
        *(uint2*)(dst + (size_t)p * 128 + cg * 4) = *(uint2*)vv;
    }
}

// ---------------- prep: W_exp fp32 [e][co][ci][3][3] -> Wt bf16 [e][co][tap*128+ci] ----------------
__global__ __launch_bounds__(256) void prep_wt(
    const float* __restrict__ Wexp, __hip_bfloat16* __restrict__ Wt)
{
    int idx = blockIdx.x * 256 + threadIdx.x;   // e*16384 + co*128 + ci
    const float* src = Wexp + (size_t)idx * 9;
    int e  = idx >> 14;
    int rem = idx & 16383;
    int co = rem >> 7, ci = rem & 127;
    __hip_bfloat16* dst = Wt + ((size_t)(e * 128 + co)) * 1152 + ci;
    #pragma unroll
    for (int tap = 0; tap < 9; ++tap)
        dst[tap * 128] = __float2bfloat16(src[tap]);
}

// ---------------- pooling ----------------
__global__ __launch_bounds__(256) void pool_kernel(
    const __hip_bfloat16* __restrict__ y, float* __restrict__ pooled)
{
    const int c = blockIdx.x;
    const int b = blockIdx.y;
    const __hip_bfloat16* src = y + ((size_t)b * 256 + 128 + c) * NPIX;
    float s = 0.f;
    for (int p = threadIdx.x; p < NPIX; p += 256)
        s += __bfloat162float(src[p]);
    #pragma unroll
    for (int off = 32; off > 0; off >>= 1)
        s += __shfl_down(s, off, 64);
    __shared__ float red[4];
    int lane = threadIdx.x & 63, wv = threadIdx.x >> 6;
    if (lane == 0) red[wv] = s;
    __syncthreads();
    if (threadIdx.x == 0) {
        float t = red[0] + red[1] + red[2] + red[3];
        pooled[b * 128 + c] = t * (1.0f / NPIX);
    }
}

// ---------------- router ----------------
__global__ __launch_bounds__(64) void router_kernel(
    const float* __restrict__ pooled, const float* __restrict__ Wr,
    const float* __restrict__ br, int* __restrict__ sel_idx, float* __restrict__ sel_w)
{
    __shared__ float lg[16][4];
    int tid = threadIdx.x;
    int b = tid >> 2, e = tid & 3;
    float s = br[e];
    for (int c2 = 0; c2 < 128; c2++)
        s += pooled[b * 128 + c2] * Wr[e * 128 + c2];
    lg[b][e] = s;
    __syncthreads();
    if (tid < 16) {
        int bb = tid;
        float l[4]; float mx = -1e30f;
        #pragma unroll
        for (int i = 0; i < 4; i++) { l[i] = lg[bb][i]; mx = fmaxf(mx, l[i]); }
        float p[4]; float sum = 0.f;
        #pragma unroll
        for (int i = 0; i < 4; i++) { p[i] = __expf(l[i] - mx); sum += p[i]; }
        #pragma unroll
        for (int i = 0; i < 4; i++) p[i] /= sum;
        int i1 = 0;
        for (int i = 1; i < 4; i++) if (p[i] > p[i1]) i1 = i;
        int i2 = (i1 == 0) ? 1 : 0;
        for (int i = 0; i < 4; i++) if (i != i1 && p[i] > p[i2]) i2 = i;
        float inv = 1.0f / (p[i1] + p[i2]);
        sel_idx[bb * 2 + 0] = i1; sel_idx[bb * 2 + 1] = i2;
        sel_w[bb * 2 + 0] = p[i1] * inv; sel_w[bb * 2 + 1] = p[i2] * inv;
    }
}

// ---------------- expert conv as implicit GEMM w/ MFMA ----------------
// D[co][pix] = sum_k Wt[e][co][k] * mT[pix shifted by tap(k)][ci(k)], K = 9*128
// grid (100 pixel-chunks of 64, 16 b); block 256 = 4 waves (2 co-groups x 2 pix-groups)
// wave: 4 m-tiles(16co) x 2 n-tiles(16pix) x 2 experts
__global__ __launch_bounds__(256, 2) void expert_gemm(
    const __hip_bfloat16* __restrict__ mT, const __hip_bfloat16* __restrict__ Wt,
    const float* __restrict__ bexp, const int* __restrict__ sel_idx,
    const float* __restrict__ sel_w, __hip_bfloat16* __restrict__ moe)
{
    const int b  = blockIdx.y;
    const int p0 = blockIdx.x * 64;
    const int e0 = sel_idx[b * 2 + 0], e1 = sel_idx[b * 2 + 1];
    const float g0 = sel_w[b * 2 + 0], g1 = sel_w[b * 2 + 1];

    __shared__ short As[2][128][72];   // [expert][co][64 k + 8 pad] = 36864 B

    const int tid  = threadIdx.x;
    const int wave = tid >> 6, lane = tid & 63;
    const int col  = lane & 15, quad = lane >> 4;
    const int wco  = (wave >> 1) * 64;     // 0 / 64
    const int wpx  = (wave & 1) * 32;      // 0 / 32

    const __hip_bfloat16* mTb = mT + (size_t)b * NPIX * 128;
    const __hip_bfloat16* wsrc0 = Wt + (size_t)e0 * 128 * 1152;
    const __hip_bfloat16* wsrc1 = Wt + (size_t)e1 * 128 * 1152;

    // per-lane output pixel coords for the 2 n-tiles
    int pp[2], prow[2], pcol[2];
    #pragma unroll
    for (int nt = 0; nt < 2; ++nt) {
        pp[nt]   = p0 + wpx + nt * 16 + col;
        prow[nt] = pp[nt] / IMW;
        pcol[nt] = pp[nt] % IMW;
    }

    floatx4 acc[2][4][2] = {};   // [expert][mt][nt]

    for (int ch = 0; ch < 18; ++ch) {
        const int tap = ch >> 1;
        const int cih = (ch & 1) << 6;          // 0 / 64
        __syncthreads();
        // stage 64-k chunk of both experts' weights into LDS
        #pragma unroll
        for (int i = 0; i < 8; ++i) {
            int idx = tid + i * 256;            // 0..2047
            int e = idx >> 10;
            int rem = idx & 1023;
            int co = rem >> 3, kg = rem & 7;
            const __hip_bfloat16* src = (e == 0 ? wsrc0 : wsrc1)
                + (size_t)co * 1152 + tap * 128 + cih + kg * 8;
            *(int4*)&As[e][co][kg * 8] = *(const int4*)src;
        }
        __syncthreads();

        // tap shift + validity per n-tile
        const int dyy = tap / 3 - 1, dxx = tap % 3 - 1;
        bool valid[2];
        const __hip_bfloat16* bbase[2];
        #pragma unroll
        for (int nt = 0; nt < 2; ++nt) {
            int ir = prow[nt] + dyy, ic = pcol[nt] + dxx;
            valid[nt] = ((unsigned)ir < IMH) && ((unsigned)ic < IMW);
            bbase[nt] = mTb + (size_t)(ir * IMW + ic) * 128 + cih + quad * 8;
        }

        #pragma unroll
        for (int ks = 0; ks < 2; ++ks) {
            short8 bf[2];
            #pragma unroll
            for (int nt = 0; nt < 2; ++nt) {
                int4 v = {0, 0, 0, 0};
                if (valid[nt]) v = *(const int4*)(bbase[nt] + ks * 32);
                bf[nt] = *(short8*)&v;
            }
            short8 af[2][4];
            #pragma unroll
            for (int e = 0; e < 2; ++e)
                #pragma unroll
                for (int mt = 0; mt < 4; ++mt)
                    af[e][mt] = *(const short8*)&As[e][wco + mt * 16 + col][ks * 32 + quad * 8];
            #pragma unroll
            for (int e = 0; e < 2; ++e)
                #pragma unroll
                for (int mt = 0; mt < 4; ++mt)
                    #pragma unroll
                    for (int nt = 0; nt < 2; ++nt)
                        acc[e][mt][nt] = __builtin_amdgcn_mfma_f32_16x16x32_bf16(
                            af[e][mt], bf[nt], acc[e][mt][nt], 0, 0, 0);
        }
    }

    // epilogue: bias + silu per expert, gate-weighted sum
    #pragma unroll
    for (int mt = 0; mt < 4; ++mt) {
        #pragma unroll
        for (int r = 0; r < 4; ++r) {
            int coo = wco + mt * 16 + quad * 4 + r;
            float b0 = bexp[e0 * 128 + coo];
            float b1 = bexp[e1 * 128 + coo];
            #pragma unroll
            for (int nt = 0; nt < 2; ++nt) {
                float v = g0 * silu_f(acc[0][mt][nt][r] + b0)
                        + g1 * silu_f(acc[1][mt][nt][r] + b1);
                moe[((size_t)b * 128 + coo) * NPIX + pp[nt]] = __float2bfloat16(v);
            }
        }
    }
}

// ---------------- cv2 ----------------
__global__ __launch_bounds__(256) void cv2_kernel(
    const __hip_bfloat16* __restrict__ y, const __hip_bfloat16* __restrict__ moe,
    const float* __restrict__ W2, const float* __restrict__ b2,
    float* __restrict__ out)
{
    const int b   = blockIdx.z;
    const int p0  = blockIdx.x * 64;
    const int co0 = blockIdx.y * 64;
    __shared__ float As[16][64];
    __shared__ float Bs[16][64];
    const int tid = threadIdx.x;
    const int tn = tid & 15;
    const int tm = tid >> 4;
    float acc[4][4] = {};
    for (int k0 = 0; k0 < 384; k0 += 16) {
        #pragma unroll
        for (int i = 0; i < 4; i++) {
            int e = tid + i * 256;
            int m = e >> 4, k = e & 15;
            As[k][m] = W2[(co0 + m) * 384 + (k0 + k)];
        }
        #pragma unroll
        for (int i = 0; i < 4; i++) {
            int e = tid + i * 256;
            int k = e >> 6, n = e & 63;
            int jch = k0 + k;
            float v;
            if (jch < 256)
                v = __bfloat162float(y[((size_t)b * 256 + jch) * NPIX + p0 + n]);
            else
                v = __bfloat162float(moe[((size_t)b * 128 + (jch - 256)) * NPIX + p0 + n]);
            Bs[k][n] = v;
        }
        __syncthreads();
        #pragma unroll
        for (int k = 0; k < 16; k++) {
            float4 av = *(const float4*)&As[k][tm * 4];
            float4 bv = *(const float4*)&Bs[k][tn * 4];
            float a[4] = {av.x, av.y, av.z, av.w};
            float bb[4] = {bv.x, bv.y, bv.z, bv.w};
            #pragma unroll
            for (int i2 = 0; i2 < 4; i2++)
                #pragma unroll
                for (int j = 0; j < 4; j++)
                    acc[i2][j] += a[i2] * bb[j];
        }
        __syncthreads();
    }
    #pragma unroll
    for (int i = 0; i < 4; i++) {
        int co = co0 + tm * 4 + i;
        float bias = b2[co];
        size_t base = ((size_t)b * 256 + co) * NPIX + p0 + tn * 4;
        #pragma unroll
        for (int j = 0; j < 4; j++) {
            float v = acc[i][j] + bias;
            out[base + j] = silu_f(v);
        }
    }
}

extern "C" void kernel_launch(void* const* d_in, const int* in_sizes, int n_in,
                              void* d_out, int out_size, void* d_ws, size_t ws_size,
                              hipStream_t stream)
{
    (void)in_sizes; (void)n_in; (void)out_size; (void)ws_size;
    const float* x    = (const float*)d_in[0];
    const float* W1   = (const float*)d_in[1];
    const float* b1   = (const float*)d_in[2];
    const float* Wr   = (const float*)d_in[3];
    const float* br   = (const float*)d_in[4];
    const float* Wexp = (const float*)d_in[5];
    const float* bexp = (const float*)d_in[6];
    const float* W2   = (const float*)d_in[7];
    const float* b2   = (const float*)d_in[8];
    float* out = (float*)d_out;

    char* ws = (char*)d_ws;
    // layout (256B aligned):
    __hip_bfloat16* y   = (__hip_bfloat16*)ws;                     // 52,428,800
    __hip_bfloat16* moe = (__hip_bfloat16*)(ws + 52428800);        // 26,214,400
    __hip_bfloat16* mT  = (__hip_bfloat16*)(ws + 78643200);        // 26,214,400
    __hip_bfloat16* Wt  = (__hip_bfloat16*)(ws + 104857600);       //  1,179,648
    float* pooled       = (float*)(ws + 106037248);                //      8,192
    int*   sel_idx      = (int*)(ws + 106045440);                  //        128
    float* sel_w        = (float*)(ws + 106045568);                //        128

    prep_wt      <<<dim3(256),          256, 0, stream>>>(Wexp, Wt);
    cv1_kernel   <<<dim3(100, 4, 16),   256, 0, stream>>>(x, W1, b1, y);
    transpose_m  <<<dim3(100, 2, 16),   256, 0, stream>>>(y, mT);
    pool_kernel  <<<dim3(128, 16),      256, 0, stream>>>(y, pooled);
    router_kernel<<<1,                   64, 0, stream>>>(pooled, Wr, br, sel_idx, sel_w);
    expert_gemm  <<<dim3(100, 16),      256, 0, stream>>>(mT, Wt, bexp, sel_idx, sel_w, moe);
    cv2_kernel   <<<dim3(100, 4, 16),   256, 0, stream>>>(y, moe, W2, b2, out);
}

// Round 3
// 564.438 us; speedup vs baseline: 4.7779x; 1.6677x over previous
//
#include <hip/hip_runtime.h>
#include <hip/hip_bf16.h>

#define NPIX 6400
#define IMW 80
#define IMH 80

typedef __attribute__((ext_vector_type(8))) short short8;
typedef __attribute__((ext_vector_type(4))) float floatx4;

__device__ __forceinline__ float silu_f(float v) {
    return v / (1.0f + __expf(-v));
}
__device__ __forceinline__ unsigned short f2bf(float v) {
    __hip_bfloat16 h = __float2bfloat16(v);
    return *(unsigned short*)&h;
}

// ---------------- prep: W1 [256][256], W2 [256][384] fp32 -> bf16 (k-contiguous already) ----
__global__ __launch_bounds__(256) void prep_small(
    const float* __restrict__ W1, const float* __restrict__ W2,
    __hip_bfloat16* __restrict__ Wt1, __hip_bfloat16* __restrict__ Wt2)
{
    int i = blockIdx.x * 256 + threadIdx.x;
    if (i < 65536) Wt1[i] = __float2bfloat16(W1[i]);
    if (i < 98304) Wt2[i] = __float2bfloat16(W2[i]);
}

// ---------------- prep: W_exp fp32 [e][co][ci][3][3] -> Wt bf16 [e][co][tap*128+ci] -------
__global__ __launch_bounds__(256) void prep_wt(
    const float* __restrict__ Wexp, __hip_bfloat16* __restrict__ Wt)
{
    int idx = blockIdx.x * 256 + threadIdx.x;   // e*16384 + co*128 + ci
    const float* src = Wexp + (size_t)idx * 9;
    int e  = idx >> 14;
    int rem = idx & 16383;
    int co = rem >> 7, ci = rem & 127;
    __hip_bfloat16* dst = Wt + ((size_t)(e * 128 + co)) * 1152 + ci;
    #pragma unroll
    for (int tap = 0; tap < 9; ++tap)
        dst[tap * 128] = __float2bfloat16(src[tap]);
}

// ---------------- cv1 as MFMA GEMM: catT[b][pix][co] = silu(W1 @ x + b1), + fused pooling --
// grid (100 pix-chunks, 16 b), block 256 = 4 waves (2 co-halves x 2 pix-halves)
// wave: 8 m-tiles(16co) x 2 n-tiles(16pix), K=256
__global__ __launch_bounds__(256) void cv1_mfma(
    const float* __restrict__ x, const __hip_bfloat16* __restrict__ Wt1,
    const float* __restrict__ b1, __hip_bfloat16* __restrict__ catT,
    float* __restrict__ pooled)
{
    const int b  = blockIdx.y;
    const int p0 = blockIdx.x * 64;
    const int tid = threadIdx.x;
    const int wave = tid >> 6, lane = tid & 63;
    const int col = lane & 15, quad = lane >> 4;
    const int cohalf = (wave >> 1) * 128;   // 0 / 128
    const int wpx    = (wave & 1) * 32;     // 0 / 32

    const float* xb = x + (size_t)b * 256 * NPIX;
    int pp[2];
    pp[0] = p0 + wpx + col;
    pp[1] = pp[0] + 16;

    floatx4 acc[8][2] = {};

    for (int k0 = 0; k0 < 256; k0 += 32) {
        // B fragments: x[k = k0+quad*8+j][pix], fp32 -> bf16 inline
        short8 bf[2];
        #pragma unroll
        for (int nt = 0; nt < 2; ++nt) {
            short8 t;
            #pragma unroll
            for (int j = 0; j < 8; ++j) {
                float xv = xb[(size_t)(k0 + quad * 8 + j) * NPIX + pp[nt]];
                t[j] = (short)f2bf(xv);
            }
            bf[nt] = t;
        }
        #pragma unroll
        for (int mt = 0; mt < 8; ++mt) {
            short8 af = *(const short8*)&Wt1[(size_t)(cohalf + mt * 16 + col) * 256
                                             + k0 + quad * 8];
            acc[mt][0] = __builtin_amdgcn_mfma_f32_16x16x32_bf16(af, bf[0], acc[mt][0], 0, 0, 0);
            acc[mt][1] = __builtin_amdgcn_mfma_f32_16x16x32_bf16(af, bf[1], acc[mt][1], 0, 0, 0);
        }
    }

    // epilogue: bias + silu, packed bf16 store to catT, fused pooling for co in [128,256)
    __hip_bfloat16* ct = catT + (size_t)b * NPIX * 384;
    #pragma unroll
    for (int mt = 0; mt < 8; ++mt) {
        const int cobase = cohalf + mt * 16 + quad * 4;
        float bias[4];
        #pragma unroll
        for (int r = 0; r < 4; ++r) bias[r] = b1[cobase + r];
        float v[2][4];
        #pragma unroll
        for (int nt = 0; nt < 2; ++nt) {
            unsigned short pk[4];
            #pragma unroll
            for (int r = 0; r < 4; ++r) {
                v[nt][r] = silu_f(acc[mt][nt][r] + bias[r]);
                pk[r] = f2bf(v[nt][r]);
            }
            *(uint2*)&ct[(size_t)pp[nt] * 384 + cobase] = *(uint2*)pk;
        }
        if (cohalf == 128) {
            #pragma unroll
            for (int r = 0; r < 4; ++r) {
                float s = v[0][r] + v[1][r];
                #pragma unroll
                for (int m = 1; m < 16; m <<= 1)
                    s += __shfl_xor(s, m, 64);
                if (col == 0)
                    atomicAdd(&pooled[b * 128 + (cobase - 128) + r], s * (1.0f / NPIX));
            }
        }
    }
}

// ---------------- router: logits -> softmax -> top2 -> renorm ----------------
__global__ __launch_bounds__(64) void router_kernel(
    const float* __restrict__ pooled, const float* __restrict__ Wr,
    const float* __restrict__ br, int* __restrict__ sel_idx, float* __restrict__ sel_w)
{
    __shared__ float lg[16][4];
    int tid = threadIdx.x;
    int b = tid >> 2, e = tid & 3;
    float s = br[e];
    for (int c2 = 0; c2 < 128; c2++)
        s += pooled[b * 128 + c2] * Wr[e * 128 + c2];
    lg[b][e] = s;
    __syncthreads();
    if (tid < 16) {
        int bb = tid;
        float l[4]; float mx = -1e30f;
        #pragma unroll
        for (int i = 0; i < 4; i++) { l[i] = lg[bb][i]; mx = fmaxf(mx, l[i]); }
        float p[4]; float sum = 0.f;
        #pragma unroll
        for (int i = 0; i < 4; i++) { p[i] = __expf(l[i] - mx); sum += p[i]; }
        #pragma unroll
        for (int i = 0; i < 4; i++) p[i] /= sum;
        int i1 = 0;
        for (int i = 1; i < 4; i++) if (p[i] > p[i1]) i1 = i;
        int i2 = (i1 == 0) ? 1 : 0;
        for (int i = 0; i < 4; i++) if (i != i1 && p[i] > p[i2]) i2 = i;
        float inv = 1.0f / (p[i1] + p[i2]);
        sel_idx[bb * 2 + 0] = i1; sel_idx[bb * 2 + 1] = i2;
        sel_w[bb * 2 + 0] = p[i1] * inv; sel_w[bb * 2 + 1] = p[i2] * inv;
    }
}

// ---------------- expert conv as implicit GEMM w/ MFMA; B and output live in catT ---------
// grid (100 pixel-chunks of 64, 16 b); block 256 = 4 waves (2 co-groups x 2 pix-groups)
__global__ __launch_bounds__(256, 2) void expert_gemm(
    __hip_bfloat16* __restrict__ catT, const __hip_bfloat16* __restrict__ Wt,
    const float* __restrict__ bexp, const int* __restrict__ sel_idx,
    const float* __restrict__ sel_w)
{
    const int b  = blockIdx.y;
    const int p0 = blockIdx.x * 64;
    const int e0 = sel_idx[b * 2 + 0], e1 = sel_idx[b * 2 + 1];
    const float g0 = sel_w[b * 2 + 0], g1 = sel_w[b * 2 + 1];

    __shared__ short As[2][128][72];   // [expert][co][64 k + 8 pad] = 36864 B

    const int tid  = threadIdx.x;
    const int wave = tid >> 6, lane = tid & 63;
    const int col  = lane & 15, quad = lane >> 4;
    const int wco  = (wave >> 1) * 64;     // 0 / 64
    const int wpx  = (wave & 1) * 32;      // 0 / 32

    __hip_bfloat16* ct = catT + (size_t)b * NPIX * 384;
    const __hip_bfloat16* wsrc0 = Wt + (size_t)e0 * 128 * 1152;
    const __hip_bfloat16* wsrc1 = Wt + (size_t)e1 * 128 * 1152;

    int pp[2], prow[2], pcol[2];
    #pragma unroll
    for (int nt = 0; nt < 2; ++nt) {
        pp[nt]   = p0 + wpx + nt * 16 + col;
        prow[nt] = pp[nt] / IMW;
        pcol[nt] = pp[nt] % IMW;
    }

    floatx4 acc[2][4][2] = {};   // [expert][mt][nt]

    for (int ch = 0; ch < 18; ++ch) {
        const int tap = ch >> 1;
        const int cih = (ch & 1) << 6;          // 0 / 64
        __syncthreads();
        #pragma unroll
        for (int i = 0; i < 8; ++i) {
            int idx = tid + i * 256;            // 0..2047
            int e = idx >> 10;
            int rem = idx & 1023;
            int co = rem >> 3, kg = rem & 7;
            const __hip_bfloat16* src = (e == 0 ? wsrc0 : wsrc1)
                + (size_t)co * 1152 + tap * 128 + cih + kg * 8;
            *(int4*)&As[e][co][kg * 8] = *(const int4*)src;
        }
        __syncthreads();

        const int dyy = tap / 3 - 1, dxx = tap % 3 - 1;
        bool valid[2];
        const __hip_bfloat16* bbase[2];
        #pragma unroll
        for (int nt = 0; nt < 2; ++nt) {
            int ir = prow[nt] + dyy, ic = pcol[nt] + dxx;
            valid[nt] = ((unsigned)ir < IMH) && ((unsigned)ic < IMW);
            bbase[nt] = ct + (size_t)(ir * IMW + ic) * 384 + 128 + cih + quad * 8;
        }

        #pragma unroll
        for (int ks = 0; ks < 2; ++ks) {
            short8 bf[2];
            #pragma unroll
            for (int nt = 0; nt < 2; ++nt) {
                int4 vv = {0, 0, 0, 0};
                if (valid[nt]) vv = *(const int4*)(bbase[nt] + ks * 32);
                bf[nt] = *(short8*)&vv;
            }
            short8 af[2][4];
            #pragma unroll
            for (int e = 0; e < 2; ++e)
                #pragma unroll
                for (int mt = 0; mt < 4; ++mt)
                    af[e][mt] = *(const short8*)&As[e][wco + mt * 16 + col][ks * 32 + quad * 8];
            #pragma unroll
            for (int e = 0; e < 2; ++e)
                #pragma unroll
                for (int mt = 0; mt < 4; ++mt)
                    #pragma unroll
                    for (int nt = 0; nt < 2; ++nt)
                        acc[e][mt][nt] = __builtin_amdgcn_mfma_f32_16x16x32_bf16(
                            af[e][mt], bf[nt], acc[e][mt][nt], 0, 0, 0);
        }
    }

    // epilogue: bias + silu per expert, gate-weighted sum -> catT[pix][256+co] (bf16 packed)
    #pragma unroll
    for (int mt = 0; mt < 4; ++mt) {
        const int cobase = wco + mt * 16 + quad * 4;
        #pragma unroll
        for (int nt = 0; nt < 2; ++nt) {
            unsigned short pk[4];
            #pragma unroll
            for (int r = 0; r < 4; ++r) {
                int coo = cobase + r;
                float vb0 = bexp[e0 * 128 + coo];
                float vb1 = bexp[e1 * 128 + coo];
                float v = g0 * silu_f(acc[0][mt][nt][r] + vb0)
                        + g1 * silu_f(acc[1][mt][nt][r] + vb1);
                pk[r] = f2bf(v);
            }
            *(uint2*)&ct[(size_t)pp[nt] * 384 + 256 + cobase] = *(uint2*)pk;
        }
    }
}

// ---------------- cv2 as MFMA GEMM: out = silu(W2 @ catT^T + b2), fp32 NCHW out -----------
// grid (100, 16), block 256 = 4 waves (2 co-halves x 2 pix-halves); K=384
__global__ __launch_bounds__(256) void cv2_mfma(
    const __hip_bfloat16* __restrict__ catT, const __hip_bfloat16* __restrict__ Wt2,
    const float* __restrict__ b2, float* __restrict__ out)
{
    const int b  = blockIdx.y;
    const int p0 = blockIdx.x * 64;
    const int tid = threadIdx.x;
    const int wave = tid >> 6, lane = tid & 63;
    const int col = lane & 15, quad = lane >> 4;
    const int cohalf = (wave >> 1) * 128;
    const int wpx    = (wave & 1) * 32;

    const __hip_bfloat16* ct = catT + (size_t)b * NPIX * 384;
    int pp[2];
    pp[0] = p0 + wpx + col;
    pp[1] = pp[0] + 16;

    floatx4 acc[8][2] = {};

    for (int k0 = 0; k0 < 384; k0 += 32) {
        short8 bf[2];
        #pragma unroll
        for (int nt = 0; nt < 2; ++nt)
            bf[nt] = *(const short8*)&ct[(size_t)pp[nt] * 384 + k0 + quad * 8];
        #pragma unroll
        for (int mt = 0; mt < 8; ++mt) {
            short8 af = *(const short8*)&Wt2[(size_t)(cohalf + mt * 16 + col) * 384
                                             + k0 + quad * 8];
            acc[mt][0] = __builtin_amdgcn_mfma_f32_16x16x32_bf16(af, bf[0], acc[mt][0], 0, 0, 0);
            acc[mt][1] = __builtin_amdgcn_mfma_f32_16x16x32_bf16(af, bf[1], acc[mt][1], 0, 0, 0);
        }
    }

    #pragma unroll
    for (int mt = 0; mt < 8; ++mt) {
        const int cobase = cohalf + mt * 16 + quad * 4;
        #pragma unroll
        for (int r = 0; r < 4; ++r) {
            float bias = b2[cobase + r];
            size_t rowb = ((size_t)b * 256 + cobase + r) * NPIX;
            #pragma unroll
            for (int nt = 0; nt < 2; ++nt)
                out[rowb + pp[nt]] = silu_f(acc[mt][nt][r] + bias);
        }
    }
}

extern "C" void kernel_launch(void* const* d_in, const int* in_sizes, int n_in,
                              void* d_out, int out_size, void* d_ws, size_t ws_size,
                              hipStream_t stream)
{
    (void)in_sizes; (void)n_in; (void)out_size; (void)ws_size;
    const float* x    = (const float*)d_in[0];
    const float* W1   = (const float*)d_in[1];
    const float* b1   = (const float*)d_in[2];
    const float* Wr   = (const float*)d_in[3];
    const float* br   = (const float*)d_in[4];
    const float* Wexp = (const float*)d_in[5];
    const float* bexp = (const float*)d_in[6];
    const float* W2   = (const float*)d_in[7];
    const float* b2   = (const float*)d_in[8];
    float* out = (float*)d_out;

    char* ws = (char*)d_ws;
    __hip_bfloat16* catT = (__hip_bfloat16*)ws;                    // 78,643,200
    __hip_bfloat16* Wt   = (__hip_bfloat16*)(ws + 78643200);       //  1,179,648
    __hip_bfloat16* Wt1  = (__hip_bfloat16*)(ws + 79822848);       //    131,072
    __hip_bfloat16* Wt2  = (__hip_bfloat16*)(ws + 79953920);       //    196,608
    float* pooled        = (float*)(ws + 80150528);                //      8,192
    int*   sel_idx       = (int*)(ws + 80158720);                  //        128
    float* sel_w         = (float*)(ws + 80158848);                //        128

    hipMemsetAsync(pooled, 0, 16 * 128 * 4, stream);
    prep_small   <<<dim3(384),        256, 0, stream>>>(W1, W2, Wt1, Wt2);
    prep_wt      <<<dim3(256),        256, 0, stream>>>(Wexp, Wt);
    cv1_mfma     <<<dim3(100, 16),    256, 0, stream>>>(x, Wt1, b1, catT, pooled);
    router_kernel<<<1,                 64, 0, stream>>>(pooled, Wr, br, sel_idx, sel_w);
    expert_gemm  <<<dim3(100, 16),    256, 0, stream>>>(catT, Wt, bexp, sel_idx, sel_w);
    cv2_mfma     <<<dim3(100, 16),    256, 0, stream>>>(catT, Wt2, b2, out);
}